// Round 1
// baseline (476.659 us; speedup 1.0000x reference)
//
#include <hip/hip_runtime.h>
#include <math.h>

#define S_LEN 4096
#define DMODEL 2048
#define NH 16
#define NKVH 4
#define HD 128
#define LDQKV 3072   // NH*HD + 2*NKVH*HD

typedef __attribute__((ext_vector_type(4))) float f32x4;
typedef __attribute__((ext_vector_type(8))) short bf16x8;
typedef __attribute__((ext_vector_type(8))) unsigned short us8;
typedef __attribute__((ext_vector_type(4))) unsigned short us4;

static __device__ __forceinline__ unsigned short f2bf(float f) {
  unsigned int u = __builtin_bit_cast(unsigned int, f);
  u += 0x7fffu + ((u >> 16) & 1u);
  return (unsigned short)(u >> 16);
}
static __device__ __forceinline__ float bf2f(unsigned short h) {
  unsigned int u = ((unsigned int)h) << 16;
  return __builtin_bit_cast(float, u);
}

#define GLDS16(g, l) __builtin_amdgcn_global_load_lds( \
    (__attribute__((address_space(1))) void*)(g), \
    (__attribute__((address_space(3))) void*)(l), 16, 0, 0)

// ---------------- prep kernels ----------------

__global__ __launch_bounds__(256) void k_cast_bf16(const float* __restrict__ src,
                                                   unsigned short* __restrict__ dst, int n4) {
  int i = blockIdx.x * 256 + threadIdx.x;
  if (i >= n4) return;
  const float4* s = (const float4*)src;
  float4 v = s[i];
  us4 o = { f2bf(v.x), f2bf(v.y), f2bf(v.z), f2bf(v.w) };
  *(us4*)(dst + (size_t)i * 4) = o;
}

// dst[n*K+k] = bf16(src[k*N+n]); K,N multiples of 64
__global__ __launch_bounds__(256) void k_transpose_bf16(const float* __restrict__ src,
    unsigned short* __restrict__ dst, int K, int N) {
  __shared__ float tile[64][65];
  int k0 = blockIdx.x * 64, n0 = blockIdx.y * 64;
  int t = threadIdx.x;
#pragma unroll
  for (int i = 0; i < 16; ++i) {
    int idx = t + i * 256;
    int r = idx >> 6, c = idx & 63;
    tile[r][c] = src[(size_t)(k0 + r) * N + n0 + c];
  }
  __syncthreads();
#pragma unroll
  for (int i = 0; i < 16; ++i) {
    int idx = t + i * 256;
    int r = idx >> 6, c = idx & 63;
    dst[(size_t)(n0 + r) * K + k0 + c] = f2bf(tile[c][r]);
  }
}

__global__ __launch_bounds__(256) void k_loggate(const float* __restrict__ g,
                                                 float* __restrict__ lg, int n) {
  int i = blockIdx.x * 256 + threadIdx.x;
  if (i < n) lg[i] = logf(g[i] + 1e-8f);
}

// in-place RoPE on Q (cols 0..2047) and K (cols 2048..2559) of QKV [S][3072]
__global__ __launch_bounds__(256) void k_rope(unsigned short* __restrict__ QKV,
    const float* __restrict__ cp, const float* __restrict__ sp) {
  int gid = blockIdx.x * 256 + threadIdx.x;   // S*20*64 total
  int d = gid & 63;
  int hh = (gid >> 6) % 20;
  int s = gid / 1280;
  int col = hh < NH ? hh * HD : DMODEL + (hh - NH) * HD;
  size_t base = (size_t)s * LDQKV + col;
  float x1 = bf2f(QKV[base + d]);
  float x2 = bf2f(QKV[base + d + 64]);
  float c1 = cp[s * HD + d], s1 = sp[s * HD + d];
  float c2 = cp[s * HD + d + 64], s2 = sp[s * HD + d + 64];
  QKV[base + d]      = f2bf(x1 * c1 - x2 * s1);
  QKV[base + d + 64] = f2bf(x2 * c2 + x1 * s2);
}

// Vt[(kvh*128+d)*S + s] = QKV[s*3072 + 2560 + kvh*128 + d]
__global__ __launch_bounds__(256) void k_transpose_v(const unsigned short* __restrict__ QKV,
    unsigned short* __restrict__ Vt) {
  __shared__ unsigned short tile[64][72];
  int s0 = blockIdx.x * 64, c0 = blockIdx.y * 64;
  int t = threadIdx.x;
#pragma unroll
  for (int i = 0; i < 16; ++i) {
    int idx = t + i * 256;
    int r = idx >> 6, c = idx & 63;
    tile[r][c] = QKV[(size_t)(s0 + r) * LDQKV + DMODEL + NKVH * HD + c0 + c];
  }
  __syncthreads();
#pragma unroll
  for (int i = 0; i < 16; ++i) {
    int idx = t + i * 256;
    int r = idx >> 6, c = idx & 63;
    Vt[(size_t)(c0 + r) * S_LEN + s0 + c] = tile[c][r];
  }
}

// ---------------- GEMM: C[M][N] = A[M][K] * Bt[N][K]^T ----------------
// 128x128 tile, BK=32, 4 waves (each 64x64), source-swizzled global_load_lds.

template<int OUTF32>
__global__ __launch_bounds__(256) void k_gemm_bt(
    const unsigned short* __restrict__ A, const unsigned short* __restrict__ Bt,
    void* __restrict__ Cp, int M, int N, int K) {
  __shared__ __attribute__((aligned(16))) unsigned short As[128 * 32];
  __shared__ __attribute__((aligned(16))) unsigned short Bs[128 * 32];
  const int t = threadIdx.x;
  const int wave = t >> 6, lane = t & 63;
  const int lr = lane & 15, lg = lane >> 4;
  const int bm = blockIdx.x * 128, bn = blockIdx.y * 128;
  const int wr = (wave >> 1) * 64, wc = (wave & 1) * 64;
  f32x4 acc[4][4];
#pragma unroll
  for (int i = 0; i < 4; ++i)
#pragma unroll
    for (int j = 0; j < 4; ++j) acc[i][j] = (f32x4){0.f, 0.f, 0.f, 0.f};

  for (int k0 = 0; k0 < K; k0 += 32) {
    __syncthreads();
#pragma unroll
    for (int i = 0; i < 2; ++i) {
      const int cb = (wave * 2 + i) * 64;      // wave-uniform chunk base
      const int c = cb + lane;
      const int row = c >> 2, kc = c & 3;
      const int ksw = (kc ^ (row & 3)) * 8;    // source-side XOR swizzle
      GLDS16(A + (size_t)(bm + row) * K + k0 + ksw, (char*)As + cb * 16);
      GLDS16(Bt + (size_t)(bn + row) * K + k0 + ksw, (char*)Bs + cb * 16);
    }
    asm volatile("s_waitcnt vmcnt(0)" ::: "memory");
    __syncthreads();
    bf16x8 af[4], bfr[4];
#pragma unroll
    for (int mi = 0; mi < 4; ++mi) {
      const int row = wr + mi * 16 + lr;
      af[mi] = *(const bf16x8*)(As + row * 32 + ((lg ^ (lr & 3)) * 8));
    }
#pragma unroll
    for (int ni = 0; ni < 4; ++ni) {
      const int row = wc + ni * 16 + lr;
      bfr[ni] = *(const bf16x8*)(Bs + row * 32 + ((lg ^ (lr & 3)) * 8));
    }
#pragma unroll
    for (int mi = 0; mi < 4; ++mi)
#pragma unroll
      for (int ni = 0; ni < 4; ++ni)
        acc[mi][ni] = __builtin_amdgcn_mfma_f32_16x16x32_bf16(af[mi], bfr[ni], acc[mi][ni], 0, 0, 0);
  }
#pragma unroll
  for (int mi = 0; mi < 4; ++mi)
#pragma unroll
    for (int ni = 0; ni < 4; ++ni)
#pragma unroll
      for (int r = 0; r < 4; ++r) {
        const int m = bm + wr + mi * 16 + lg * 4 + r;
        const int n = bn + wc + ni * 16 + lr;
        if (OUTF32) ((float*)Cp)[(size_t)m * N + n] = acc[mi][ni][r];
        else ((unsigned short*)Cp)[(size_t)m * N + n] = f2bf(acc[mi][ni][r]);
      }
}

// ---------------- fused causal gated attention ----------------
// grid (S/64, NH); 4 waves, each owns 16 q-rows; KV tile = 64.

__global__ __launch_bounds__(256) void k_attn(
    const unsigned short* __restrict__ QKV, const unsigned short* __restrict__ Vt,
    const float* __restrict__ logg, unsigned short* __restrict__ Oattn) {
  __shared__ __attribute__((aligned(16))) unsigned short Ks[64 * 128];
  __shared__ __attribute__((aligned(16))) unsigned short Vs[128 * 64];
  __shared__ __attribute__((aligned(16))) unsigned short Ps[4][16][72];
  const int h = blockIdx.y, kvh = h >> 2;
  const int bx = blockIdx.x, q0 = bx * 64;
  const int t = threadIdx.x, wave = t >> 6, lane = t & 63;
  const int lr = lane & 15, lg = lane >> 4;
  const unsigned short* Qp = QKV + h * HD;
  const unsigned short* Kp = QKV + DMODEL + kvh * HD;
  const unsigned short* Vp = Vt + (size_t)kvh * HD * S_LEN;

  bf16x8 qf[4];
  {
    const size_t qoff = (size_t)(q0 + wave * 16 + lr) * LDQKV;
#pragma unroll
    for (int ks = 0; ks < 4; ++ks)
      qf[ks] = *(const bf16x8*)(Qp + qoff + ks * 32 + lg * 8);
  }
  f32x4 acc[8];
#pragma unroll
  for (int j = 0; j < 8; ++j) acc[j] = (f32x4){0.f, 0.f, 0.f, 0.f};
  float mrow[4] = {-3e38f, -3e38f, -3e38f, -3e38f};
  float srow[4] = {0.f, 0.f, 0.f, 0.f};
  const float scale = 0.08838834764831845f;  // 1/sqrt(128)
  const int qbase = q0 + wave * 16 + lg * 4;

  for (int kt = 0; kt <= bx; ++kt) {
    const int kv0 = kt * 64;
    __syncthreads();
    // stage K [64][128] and V^T [128][64], source-swizzled, async
#pragma unroll
    for (int i = 0; i < 4; ++i) {
      const int cb = (wave * 4 + i) * 64;
      const int c = cb + lane;
      {
        const int row = c >> 4, kc = c & 15;
        GLDS16(Kp + (size_t)(kv0 + row) * LDQKV + ((kc ^ (row & 7)) * 8), (char*)Ks + cb * 16);
      }
      {
        const int d = c >> 3, kc = c & 7;
        GLDS16(Vp + (size_t)d * S_LEN + kv0 + ((kc ^ (d & 7)) * 8), (char*)Vs + cb * 16);
      }
    }
    asm volatile("s_waitcnt vmcnt(0)" ::: "memory");
    __syncthreads();

    // Q.K^T : 16x64 scores per wave
    f32x4 sc[4];
#pragma unroll
    for (int cf = 0; cf < 4; ++cf) {
      sc[cf] = (f32x4){0.f, 0.f, 0.f, 0.f};
      const int row = cf * 16 + lr;
#pragma unroll
      for (int ks = 0; ks < 4; ++ks) {
        bf16x8 kb = *(const bf16x8*)(Ks + row * 128 + (((ks * 4 + lg) ^ (lr & 7)) * 8));
        sc[cf] = __builtin_amdgcn_mfma_f32_16x16x32_bf16(qf[ks], kb, sc[cf], 0, 0, 0);
      }
    }
    // online softmax (rows live at (l>>4)*4+r, cols at l&15 + 16*cf)
    float lgg[4];
#pragma unroll
    for (int cf = 0; cf < 4; ++cf) lgg[cf] = logg[kv0 + cf * 16 + lr];
    float p[4][4], tm[4];
#pragma unroll
    for (int r = 0; r < 4; ++r) tm[r] = -3e38f;
#pragma unroll
    for (int cf = 0; cf < 4; ++cf) {
      const int kpos = kv0 + cf * 16 + lr;
#pragma unroll
      for (int r = 0; r < 4; ++r) {
        float v = sc[cf][r] * scale + lgg[cf];
        v = (kpos <= qbase + r) ? v : -3e38f;
        p[cf][r] = v;
        tm[r] = fmaxf(tm[r], v);
      }
    }
#pragma unroll
    for (int off = 8; off; off >>= 1)
#pragma unroll
      for (int r = 0; r < 4; ++r) tm[r] = fmaxf(tm[r], __shfl_xor(tm[r], off));
    float alpha[4], rs[4];
#pragma unroll
    for (int r = 0; r < 4; ++r) {
      const float mn = fmaxf(mrow[r], tm[r]);
      alpha[r] = __expf(mrow[r] - mn);
      mrow[r] = mn;
      rs[r] = 0.f;
    }
#pragma unroll
    for (int cf = 0; cf < 4; ++cf)
#pragma unroll
      for (int r = 0; r < 4; ++r) {
        const float e = __expf(p[cf][r] - mrow[r]);
        p[cf][r] = e;
        rs[r] += e;
      }
#pragma unroll
    for (int off = 8; off; off >>= 1)
#pragma unroll
      for (int r = 0; r < 4; ++r) rs[r] += __shfl_xor(rs[r], off);
#pragma unroll
    for (int r = 0; r < 4; ++r) srow[r] = srow[r] * alpha[r] + rs[r];
#pragma unroll
    for (int j = 0; j < 8; ++j)
#pragma unroll
      for (int r = 0; r < 4; ++r) acc[j][r] = acc[j][r] * alpha[r];
    // P -> LDS (per-wave transpose for the PV A-fragment)
#pragma unroll
    for (int cf = 0; cf < 4; ++cf)
#pragma unroll
      for (int r = 0; r < 4; ++r)
        Ps[wave][lg * 4 + r][cf * 16 + lr] = f2bf(p[cf][r]);
    asm volatile("s_waitcnt lgkmcnt(0)" ::: "memory");
    __builtin_amdgcn_sched_barrier(0);
    // P.V : accumulate 16x128
#pragma unroll
    for (int ks = 0; ks < 2; ++ks) {
      bf16x8 pa = *(const bf16x8*)(&Ps[wave][lr][ks * 32 + lg * 8]);
#pragma unroll
      for (int j = 0; j < 8; ++j) {
        const int d = j * 16 + lr;
        bf16x8 vb = *(const bf16x8*)(Vs + d * 64 + (((ks * 4 + lg) ^ (lr & 7)) * 8));
        acc[j] = __builtin_amdgcn_mfma_f32_16x16x32_bf16(pa, vb, acc[j], 0, 0, 0);
      }
    }
  }
  float inv[4];
#pragma unroll
  for (int r = 0; r < 4; ++r) inv[r] = 1.0f / srow[r];
#pragma unroll
  for (int j = 0; j < 8; ++j)
#pragma unroll
    for (int r = 0; r < 4; ++r) {
      const int m = qbase + r;
      Oattn[(size_t)m * DMODEL + h * HD + j * 16 + lr] = f2bf(acc[j][r] * inv[r]);
    }
}

// ---------------- launch ----------------

extern "C" void kernel_launch(void* const* d_in, const int* in_sizes, int n_in,
                              void* d_out, int out_size, void* d_ws, size_t ws_size,
                              hipStream_t stream) {
  (void)in_sizes; (void)n_in; (void)out_size; (void)ws_size;
  const float* hid  = (const float*)d_in[0];
  // d_in[1] = attention_mask (pure causal; recomputed inline, never read)
  const float* cosp = (const float*)d_in[2];
  const float* sinp = (const float*)d_in[3];
  const float* gate = (const float*)d_in[4];
  const float* Wq   = (const float*)d_in[5];
  const float* Wk   = (const float*)d_in[6];
  const float* Wv   = (const float*)d_in[7];
  const float* Wo   = (const float*)d_in[8];
  float* out = (float*)d_out;
  char* ws = (char*)d_ws;
  unsigned short* Xb   = (unsigned short*)(ws);                       // 16 MB  [4096][2048] bf16
  unsigned short* Wt   = (unsigned short*)(ws + (size_t)16777216);    // 12 MB  [3072][2048] bf16 (Wq|Wk|Wv)^T
  unsigned short* Wot  = (unsigned short*)(ws + (size_t)29360128);    //  8 MB  [2048][2048] bf16 Wo^T
  unsigned short* QKV  = (unsigned short*)(ws + (size_t)37748736);    // 24 MB  [4096][3072] bf16
  unsigned short* Oatt = (unsigned short*)(ws + (size_t)62914560);    // 16 MB  [4096][2048] bf16
  float* logg          = (float*)(ws + (size_t)79691776);             // 16 KB
  unsigned short* Vt   = (unsigned short*)(ws + (size_t)79708160);    //  4 MB  [4][128][4096] bf16

  k_cast_bf16<<<8192, 256, 0, stream>>>(hid, Xb, 2097152);
  k_transpose_bf16<<<dim3(32, 32), 256, 0, stream>>>(Wq, Wt, 2048, 2048);
  k_transpose_bf16<<<dim3(32, 8), 256, 0, stream>>>(Wk, Wt + (size_t)2048 * 2048, 2048, 512);
  k_transpose_bf16<<<dim3(32, 8), 256, 0, stream>>>(Wv, Wt + (size_t)2560 * 2048, 2048, 512);
  k_transpose_bf16<<<dim3(32, 32), 256, 0, stream>>>(Wo, Wot, 2048, 2048);
  k_loggate<<<16, 256, 0, stream>>>(gate, logg, 4096);
  k_gemm_bt<0><<<dim3(32, 24), 256, 0, stream>>>(Xb, Wt, QKV, 4096, 3072, 2048);
  k_rope<<<20480, 256, 0, stream>>>(QKV, cosp, sinp);
  k_transpose_v<<<dim3(64, 8), 256, 0, stream>>>(QKV, Vt);
  k_attn<<<dim3(64, 16), 256, 0, stream>>>(QKV, Vt, logg, Oatt);
  k_gemm_bt<1><<<dim3(32, 16), 256, 0, stream>>>(Oatt, Wot, out, 4096, 2048, 2048);
}

// Round 2
// 322.723 us; speedup vs baseline: 1.4770x; 1.4770x over previous
//
#include <hip/hip_runtime.h>
#include <math.h>

#define S_LEN 4096
#define DMODEL 2048
#define NH 16
#define NKVH 4
#define HD 128
#define LDQKV 3072   // NH*HD + 2*NKVH*HD

typedef __attribute__((ext_vector_type(4))) float f32x4;
typedef __attribute__((ext_vector_type(8))) short bf16x8;
typedef __attribute__((ext_vector_type(8))) unsigned short us8;
typedef __attribute__((ext_vector_type(4))) unsigned short us4;

static __device__ __forceinline__ unsigned short f2bf(float f) {
  unsigned int u = __builtin_bit_cast(unsigned int, f);
  u += 0x7fffu + ((u >> 16) & 1u);
  return (unsigned short)(u >> 16);
}
static __device__ __forceinline__ float bf2f(unsigned short h) {
  unsigned int u = ((unsigned int)h) << 16;
  return __builtin_bit_cast(float, u);
}

#define GLDS16(g, l) __builtin_amdgcn_global_load_lds( \
    (__attribute__((address_space(1))) void*)(g), \
    (__attribute__((address_space(3))) void*)(l), 16, 0, 0)

// ---------------- prep kernels ----------------

__global__ __launch_bounds__(256) void k_cast_bf16(const float* __restrict__ src,
                                                   unsigned short* __restrict__ dst, int n4) {
  int i = blockIdx.x * 256 + threadIdx.x;
  if (i >= n4) return;
  const float4* s = (const float4*)src;
  float4 v = s[i];
  us4 o = { f2bf(v.x), f2bf(v.y), f2bf(v.z), f2bf(v.w) };
  *(us4*)(dst + (size_t)i * 4) = o;
}

// dst[n*K+k] = bf16(src[k*N+n]); K,N multiples of 64
__global__ __launch_bounds__(256) void k_transpose_bf16(const float* __restrict__ src,
    unsigned short* __restrict__ dst, int K, int N) {
  __shared__ float tile[64][65];
  int k0 = blockIdx.x * 64, n0 = blockIdx.y * 64;
  int t = threadIdx.x;
#pragma unroll
  for (int i = 0; i < 16; ++i) {
    int idx = t + i * 256;
    int r = idx >> 6, c = idx & 63;
    tile[r][c] = src[(size_t)(k0 + r) * N + n0 + c];
  }
  __syncthreads();
#pragma unroll
  for (int i = 0; i < 16; ++i) {
    int idx = t + i * 256;
    int r = idx >> 6, c = idx & 63;
    dst[(size_t)(n0 + r) * K + k0 + c] = f2bf(tile[c][r]);
  }
}

__global__ __launch_bounds__(256) void k_loggate(const float* __restrict__ g,
                                                 float* __restrict__ lg, int n) {
  int i = blockIdx.x * 256 + threadIdx.x;
  if (i < n) lg[i] = logf(g[i] + 1e-8f);
}

// in-place RoPE on Q (cols 0..2047) and K (cols 2048..2559) of QKV [S][3072]
// Q additionally scaled by 1/sqrt(HD) (folded out of the attention kernel).
__global__ __launch_bounds__(256) void k_rope(unsigned short* __restrict__ QKV,
    const float* __restrict__ cp, const float* __restrict__ sp) {
  int gid = blockIdx.x * 256 + threadIdx.x;   // S*20*64 total
  int d = gid & 63;
  int hh = (gid >> 6) % 20;
  int s = gid / 1280;
  int col = hh < NH ? hh * HD : DMODEL + (hh - NH) * HD;
  float qs = hh < NH ? 0.08838834764831845f : 1.0f;  // 1/sqrt(128) for Q heads
  size_t base = (size_t)s * LDQKV + col;
  float x1 = bf2f(QKV[base + d]);
  float x2 = bf2f(QKV[base + d + 64]);
  float c1 = cp[s * HD + d], s1 = sp[s * HD + d];
  float c2 = cp[s * HD + d + 64], s2 = sp[s * HD + d + 64];
  QKV[base + d]      = f2bf((x1 * c1 - x2 * s1) * qs);
  QKV[base + d + 64] = f2bf((x2 * c2 + x1 * s2) * qs);
}

// Vt[(kvh*128+d)*S + s] = QKV[s*3072 + 2560 + kvh*128 + d]
__global__ __launch_bounds__(256) void k_transpose_v(const unsigned short* __restrict__ QKV,
    unsigned short* __restrict__ Vt) {
  __shared__ unsigned short tile[64][72];
  int s0 = blockIdx.x * 64, c0 = blockIdx.y * 64;
  int t = threadIdx.x;
#pragma unroll
  for (int i = 0; i < 16; ++i) {
    int idx = t + i * 256;
    int r = idx >> 6, c = idx & 63;
    tile[r][c] = QKV[(size_t)(s0 + r) * LDQKV + DMODEL + NKVH * HD + c0 + c];
  }
  __syncthreads();
#pragma unroll
  for (int i = 0; i < 16; ++i) {
    int idx = t + i * 256;
    int r = idx >> 6, c = idx & 63;
    Vt[(size_t)(c0 + r) * S_LEN + s0 + c] = tile[c][r];
  }
}

// ---------------- GEMM: C[M][N] = A[M][K] * Bt[N][K]^T ----------------
// 128x128 tile, BK=32, 4 waves (each 64x64), source-swizzled global_load_lds.

template<int OUTF32>
__global__ __launch_bounds__(256) void k_gemm_bt(
    const unsigned short* __restrict__ A, const unsigned short* __restrict__ Bt,
    void* __restrict__ Cp, int M, int N, int K) {
  __shared__ __attribute__((aligned(16))) unsigned short As[128 * 32];
  __shared__ __attribute__((aligned(16))) unsigned short Bs[128 * 32];
  const int t = threadIdx.x;
  const int wave = t >> 6, lane = t & 63;
  const int lr = lane & 15, lg = lane >> 4;
  const int bm = blockIdx.x * 128, bn = blockIdx.y * 128;
  const int wr = (wave >> 1) * 64, wc = (wave & 1) * 64;
  f32x4 acc[4][4];
#pragma unroll
  for (int i = 0; i < 4; ++i)
#pragma unroll
    for (int j = 0; j < 4; ++j) acc[i][j] = (f32x4){0.f, 0.f, 0.f, 0.f};

  for (int k0 = 0; k0 < K; k0 += 32) {
    __syncthreads();
#pragma unroll
    for (int i = 0; i < 2; ++i) {
      const int cb = (wave * 2 + i) * 64;      // wave-uniform chunk base
      const int c = cb + lane;
      const int row = c >> 2, kc = c & 3;
      const int ksw = (kc ^ (row & 3)) * 8;    // source-side XOR swizzle
      GLDS16(A + (size_t)(bm + row) * K + k0 + ksw, (char*)As + cb * 16);
      GLDS16(Bt + (size_t)(bn + row) * K + k0 + ksw, (char*)Bs + cb * 16);
    }
    asm volatile("s_waitcnt vmcnt(0)" ::: "memory");
    __syncthreads();
    bf16x8 af[4], bfr[4];
#pragma unroll
    for (int mi = 0; mi < 4; ++mi) {
      const int row = wr + mi * 16 + lr;
      af[mi] = *(const bf16x8*)(As + row * 32 + ((lg ^ (lr & 3)) * 8));
    }
#pragma unroll
    for (int ni = 0; ni < 4; ++ni) {
      const int row = wc + ni * 16 + lr;
      bfr[ni] = *(const bf16x8*)(Bs + row * 32 + ((lg ^ (lr & 3)) * 8));
    }
#pragma unroll
    for (int mi = 0; mi < 4; ++mi)
#pragma unroll
      for (int ni = 0; ni < 4; ++ni)
        acc[mi][ni] = __builtin_amdgcn_mfma_f32_16x16x32_bf16(af[mi], bfr[ni], acc[mi][ni], 0, 0, 0);
  }
#pragma unroll
  for (int mi = 0; mi < 4; ++mi)
#pragma unroll
    for (int ni = 0; ni < 4; ++ni)
#pragma unroll
      for (int r = 0; r < 4; ++r) {
        const int m = bm + wr + mi * 16 + lg * 4 + r;
        const int n = bn + wc + ni * 16 + lr;
        if (OUTF32) ((float*)Cp)[(size_t)m * N + n] = acc[mi][ni][r];
        else ((unsigned short*)Cp)[(size_t)m * N + n] = f2bf(acc[mi][ni][r]);
      }
}

// ---------------- fused causal gated attention (v2) ----------------
// grid (32, NH); block bx handles q-tiles (63-bx) then (bx) -> 65 KV-iters/block.
// K/V double-buffered in LDS, counted vmcnt, raw s_barrier (no drain in loop).

#define STAGE_KV(kt_, buf_) do { \
  const int kv0_ = (kt_) * 64; \
  _Pragma("unroll") \
  for (int i_ = 0; i_ < 4; ++i_) { \
    const int cb_ = (wave * 4 + i_) * 64; \
    const int c_ = cb_ + lane; \
    { const int row_ = c_ >> 4, kc_ = c_ & 15; \
      GLDS16(Kp + (size_t)(kv0_ + row_) * LDQKV + ((kc_ ^ (row_ & 7)) * 8), \
             (char*)Ks[buf_] + cb_ * 16); } \
    { const int d_ = c_ >> 3, kc_ = c_ & 7; \
      GLDS16(Vp + (size_t)d_ * S_LEN + kv0_ + ((kc_ ^ (d_ & 7)) * 8), \
             (char*)Vs[buf_] + cb_ * 16); } \
  } \
} while (0)

__global__ __launch_bounds__(256) void k_attn(
    const unsigned short* __restrict__ QKV, const unsigned short* __restrict__ Vt,
    const float* __restrict__ logg, unsigned short* __restrict__ Oattn) {
  __shared__ __attribute__((aligned(16))) unsigned short Ks[2][64 * 128];
  __shared__ __attribute__((aligned(16))) unsigned short Vs[2][128 * 64];
  __shared__ __attribute__((aligned(16))) unsigned short Ps[4][16][72];
  const int h = blockIdx.y, kvh = h >> 2;
  const int bx = blockIdx.x;           // 0..31
  const int t = threadIdx.x, wave = t >> 6, lane = t & 63;
  const int lr = lane & 15, lg = lane >> 4;
  const unsigned short* Qp = QKV + h * HD;
  const unsigned short* Kp = QKV + DMODEL + kvh * HD;
  const unsigned short* Vp = Vt + (size_t)kvh * HD * S_LEN;

  for (int half = 0; half < 2; ++half) {
    const int qt = half ? bx : (63 - bx);   // heavy tile first
    const int q0 = qt * 64;
    const int nt = qt + 1;                  // causal: KV tiles 0..qt
    const int qbase = q0 + wave * 16 + lg * 4;

    bf16x8 qf[4];
    {
      const size_t qoff = (size_t)(q0 + wave * 16 + lr) * LDQKV;
#pragma unroll
      for (int ks = 0; ks < 4; ++ks)
        qf[ks] = *(const bf16x8*)(Qp + qoff + ks * 32 + lg * 8);
    }
    f32x4 acc[8];
#pragma unroll
    for (int j = 0; j < 8; ++j) acc[j] = (f32x4){0.f, 0.f, 0.f, 0.f};
    float mrow[4] = {-3e38f, -3e38f, -3e38f, -3e38f};
    float srow[4] = {0.f, 0.f, 0.f, 0.f};

    __builtin_amdgcn_s_barrier();        // protect buf0 from previous half's reads
    STAGE_KV(0, 0);

    for (int kt = 0; kt < nt; ++kt) {
      const int kv0 = kt * 64;
      if (kt + 1 < nt) {
        STAGE_KV(kt + 1, (kt + 1) & 1);
        asm volatile("s_waitcnt vmcnt(8)" ::: "memory");  // tile kt's 8 loads done
      } else {
        asm volatile("s_waitcnt vmcnt(0)" ::: "memory");
      }
      __builtin_amdgcn_s_barrier();
      const unsigned short* Kb = Ks[kt & 1];
      const unsigned short* Vb = Vs[kt & 1];

      // Q.K^T : 16x64 scores per wave
      f32x4 sc[4];
#pragma unroll
      for (int cf = 0; cf < 4; ++cf) {
        sc[cf] = (f32x4){0.f, 0.f, 0.f, 0.f};
        const int row = cf * 16 + lr;
#pragma unroll
        for (int ks = 0; ks < 4; ++ks) {
          bf16x8 kb = *(const bf16x8*)(Kb + row * 128 + (((ks * 4 + lg) ^ (lr & 7)) * 8));
          sc[cf] = __builtin_amdgcn_mfma_f32_16x16x32_bf16(qf[ks], kb, sc[cf], 0, 0, 0);
        }
      }
      // online softmax; scale pre-folded into Q, gate additive
      float lgg[4];
#pragma unroll
      for (int cf = 0; cf < 4; ++cf) lgg[cf] = logg[kv0 + cf * 16 + lr];
      float p[4][4], lmax[4] = {-3e38f, -3e38f, -3e38f, -3e38f};
#pragma unroll
      for (int cf = 0; cf < 4; ++cf) {
        const int kpos = kv0 + cf * 16 + lr;
#pragma unroll
        for (int r = 0; r < 4; ++r) {
          float v = sc[cf][r] + lgg[cf];
          v = (kpos <= qbase + r) ? v : -3e38f;
          p[cf][r] = v;
          lmax[r] = fmaxf(lmax[r], v);
        }
      }
      // defer-max: full rescale only when some row max grew past m+8
      bool need = (lmax[0] > mrow[0] + 8.f) | (lmax[1] > mrow[1] + 8.f) |
                  (lmax[2] > mrow[2] + 8.f) | (lmax[3] > mrow[3] + 8.f);
      if (__any(need)) {
        float tm[4] = {lmax[0], lmax[1], lmax[2], lmax[3]};
#pragma unroll
        for (int off = 8; off; off >>= 1)
#pragma unroll
          for (int r = 0; r < 4; ++r) tm[r] = fmaxf(tm[r], __shfl_xor(tm[r], off));
#pragma unroll
        for (int r = 0; r < 4; ++r) {
          const float mn = fmaxf(mrow[r], tm[r]);
          const float alpha = __expf(mrow[r] - mn);
          mrow[r] = mn;
          srow[r] *= alpha;
#pragma unroll
          for (int j = 0; j < 8; ++j) acc[j][r] *= alpha;
        }
      }
      float rs[4] = {0.f, 0.f, 0.f, 0.f};
#pragma unroll
      for (int cf = 0; cf < 4; ++cf)
#pragma unroll
        for (int r = 0; r < 4; ++r) {
          const float e = __expf(p[cf][r] - mrow[r]);
          p[cf][r] = e;
          rs[r] += e;
        }
#pragma unroll
      for (int off = 8; off; off >>= 1)
#pragma unroll
        for (int r = 0; r < 4; ++r) rs[r] += __shfl_xor(rs[r], off);
#pragma unroll
      for (int r = 0; r < 4; ++r) srow[r] += rs[r];
      // P -> LDS (per-wave transpose for the PV A-fragment)
#pragma unroll
      for (int cf = 0; cf < 4; ++cf)
#pragma unroll
        for (int r = 0; r < 4; ++r)
          Ps[wave][lg * 4 + r][cf * 16 + lr] = f2bf(p[cf][r]);
      asm volatile("s_waitcnt lgkmcnt(0)" ::: "memory");
      __builtin_amdgcn_sched_barrier(0);
      // P.V : accumulate 16x128
#pragma unroll
      for (int ks = 0; ks < 2; ++ks) {
        bf16x8 pa = *(const bf16x8*)(&Ps[wave][lr][ks * 32 + lg * 8]);
#pragma unroll
        for (int j = 0; j < 8; ++j) {
          const int d = j * 16 + lr;
          bf16x8 vb = *(const bf16x8*)(Vb + d * 64 + (((ks * 4 + lg) ^ (lr & 7)) * 8));
          acc[j] = __builtin_amdgcn_mfma_f32_16x16x32_bf16(pa, vb, acc[j], 0, 0, 0);
        }
      }
      __builtin_amdgcn_s_barrier();
    }

    float inv[4];
#pragma unroll
    for (int r = 0; r < 4; ++r) inv[r] = 1.0f / srow[r];
#pragma unroll
    for (int j = 0; j < 8; ++j)
#pragma unroll
      for (int r = 0; r < 4; ++r) {
        const int m = qbase + r;
        Oattn[(size_t)m * DMODEL + h * HD + j * 16 + lr] = f2bf(acc[j][r] * inv[r]);
      }
  }
}

// ---------------- launch ----------------

extern "C" void kernel_launch(void* const* d_in, const int* in_sizes, int n_in,
                              void* d_out, int out_size, void* d_ws, size_t ws_size,
                              hipStream_t stream) {
  (void)in_sizes; (void)n_in; (void)out_size; (void)ws_size;
  const float* hid  = (const float*)d_in[0];
  // d_in[1] = attention_mask (pure causal; recomputed inline, never read)
  const float* cosp = (const float*)d_in[2];
  const float* sinp = (const float*)d_in[3];
  const float* gate = (const float*)d_in[4];
  const float* Wq   = (const float*)d_in[5];
  const float* Wk   = (const float*)d_in[6];
  const float* Wv   = (const float*)d_in[7];
  const float* Wo   = (const float*)d_in[8];
  float* out = (float*)d_out;
  char* ws = (char*)d_ws;
  unsigned short* Xb   = (unsigned short*)(ws);                       // 16 MB  [4096][2048] bf16
  unsigned short* Wt   = (unsigned short*)(ws + (size_t)16777216);    // 12 MB  [3072][2048] bf16 (Wq|Wk|Wv)^T
  unsigned short* Wot  = (unsigned short*)(ws + (size_t)29360128);    //  8 MB  [2048][2048] bf16 Wo^T
  unsigned short* QKV  = (unsigned short*)(ws + (size_t)37748736);    // 24 MB  [4096][3072] bf16
  unsigned short* Oatt = (unsigned short*)(ws + (size_t)62914560);    // 16 MB  [4096][2048] bf16
  float* logg          = (float*)(ws + (size_t)79691776);             // 16 KB
  unsigned short* Vt   = (unsigned short*)(ws + (size_t)79708160);    //  4 MB  [4][128][4096] bf16

  k_cast_bf16<<<8192, 256, 0, stream>>>(hid, Xb, 2097152);
  k_transpose_bf16<<<dim3(32, 32), 256, 0, stream>>>(Wq, Wt, 2048, 2048);
  k_transpose_bf16<<<dim3(32, 8), 256, 0, stream>>>(Wk, Wt + (size_t)2048 * 2048, 2048, 512);
  k_transpose_bf16<<<dim3(32, 8), 256, 0, stream>>>(Wv, Wt + (size_t)2560 * 2048, 2048, 512);
  k_transpose_bf16<<<dim3(32, 32), 256, 0, stream>>>(Wo, Wot, 2048, 2048);
  k_loggate<<<16, 256, 0, stream>>>(gate, logg, 4096);
  k_gemm_bt<0><<<dim3(32, 24), 256, 0, stream>>>(Xb, Wt, QKV, 4096, 3072, 2048);
  k_rope<<<20480, 256, 0, stream>>>(QKV, cosp, sinp);
  k_transpose_v<<<dim3(64, 8), 256, 0, stream>>>(QKV, Vt);
  k_attn<<<dim3(32, 16), 256, 0, stream>>>(QKV, Vt, logg, Oatt);
  k_gemm_bt<1><<<dim3(32, 16), 256, 0, stream>>>(Oatt, Wot, out, 4096, 2048, 2048);
}

// Round 3
// 280.988 us; speedup vs baseline: 1.6964x; 1.1485x over previous
//
#include <hip/hip_runtime.h>
#include <math.h>

#define S_LEN 4096
#define DMODEL 2048
#define NH 16
#define NKVH 4
#define HD 128
#define LDQKV 3072   // NH*HD + 2*NKVH*HD

typedef __attribute__((ext_vector_type(4))) float f32x4;
typedef __attribute__((ext_vector_type(8))) short bf16x8;
typedef __attribute__((ext_vector_type(4))) unsigned short us4;

static __device__ __forceinline__ unsigned short f2bf(float f) {
  unsigned int u = __builtin_bit_cast(unsigned int, f);
  u += 0x7fffu + ((u >> 16) & 1u);
  return (unsigned short)(u >> 16);
}
static __device__ __forceinline__ float bf2f(unsigned short h) {
  unsigned int u = ((unsigned int)h) << 16;
  return __builtin_bit_cast(float, u);
}
static __device__ __forceinline__ unsigned int cvt_pk_bf16(float lo, float hi) {
  unsigned int r;
  asm("v_cvt_pk_bf16_f32 %0, %1, %2" : "=v"(r) : "v"(lo), "v"(hi));
  return r;
}

#define GLDS16(g, l) __builtin_amdgcn_global_load_lds( \
    (__attribute__((address_space(1))) void*)(g), \
    (__attribute__((address_space(3))) void*)(l), 16, 0, 0)

// ---------------- prep kernels ----------------

__global__ __launch_bounds__(256) void k_cast_bf16(const float* __restrict__ src,
                                                   unsigned short* __restrict__ dst, int n4) {
  int i = blockIdx.x * 256 + threadIdx.x;
  if (i >= n4) return;
  const float4* s = (const float4*)src;
  float4 v = s[i];
  us4 o = { f2bf(v.x), f2bf(v.y), f2bf(v.z), f2bf(v.w) };
  *(us4*)(dst + (size_t)i * 4) = o;
}

// dst[n*K+k] = bf16(src[k*N+n]); K,N multiples of 64
__global__ __launch_bounds__(256) void k_transpose_bf16(const float* __restrict__ src,
    unsigned short* __restrict__ dst, int K, int N) {
  __shared__ float tile[64][65];
  int k0 = blockIdx.x * 64, n0 = blockIdx.y * 64;
  int t = threadIdx.x;
#pragma unroll
  for (int i = 0; i < 16; ++i) {
    int idx = t + i * 256;
    int r = idx >> 6, c = idx & 63;
    tile[r][c] = src[(size_t)(k0 + r) * N + n0 + c];
  }
  __syncthreads();
#pragma unroll
  for (int i = 0; i < 16; ++i) {
    int idx = t + i * 256;
    int r = idx >> 6, c = idx & 63;
    dst[(size_t)(n0 + r) * K + k0 + c] = f2bf(tile[c][r]);
  }
}

// in-place RoPE on Q (cols 0..2047) and K (cols 2048..2559) of QKV [S][3072]
// Q additionally scaled by log2(e)/sqrt(HD) (exp2-domain softmax).
__global__ __launch_bounds__(256) void k_rope(unsigned short* __restrict__ QKV,
    const float* __restrict__ cp, const float* __restrict__ sp) {
  int gid = blockIdx.x * 256 + threadIdx.x;   // S*20*64 total
  int d = gid & 63;
  int hh = (gid >> 6) % 20;
  int s = gid / 1280;
  int col = hh < NH ? hh * HD : DMODEL + (hh - NH) * HD;
  float qs = hh < NH ? 0.12751589341664477f : 1.0f;  // log2e/sqrt(128) for Q heads
  size_t base = (size_t)s * LDQKV + col;
  float x1 = bf2f(QKV[base + d]);
  float x2 = bf2f(QKV[base + d + 64]);
  float c1 = cp[s * HD + d], s1 = sp[s * HD + d];
  float c2 = cp[s * HD + d + 64], s2 = sp[s * HD + d + 64];
  QKV[base + d]      = f2bf((x1 * c1 - x2 * s1) * qs);
  QKV[base + d + 64] = f2bf((x2 * c2 + x1 * s2) * qs);
}

// Vt[(kvh*128+d)*S + blk*64 + c] = QKV[blk*64 + pi(c)][2560 + kvh*128 + d]
// pi(c) = (c&3)*16 + (c>>2)  — k-permutation matching the P storage layout.
__global__ __launch_bounds__(256) void k_transpose_v(const unsigned short* __restrict__ QKV,
    unsigned short* __restrict__ Vt) {
  __shared__ unsigned short tile[64][72];
  int s0 = blockIdx.x * 64, c0 = blockIdx.y * 64;
  int t = threadIdx.x;
#pragma unroll
  for (int i = 0; i < 16; ++i) {
    int idx = t + i * 256;
    int r = idx >> 6, c = idx & 63;
    tile[r][c] = QKV[(size_t)(s0 + r) * LDQKV + DMODEL + NKVH * HD + c0 + c];
  }
  __syncthreads();
#pragma unroll
  for (int i = 0; i < 16; ++i) {
    int idx = t + i * 256;
    int r = idx >> 6, c = idx & 63;
    int pc = (c & 3) * 16 + (c >> 2);
    Vt[(size_t)(c0 + r) * S_LEN + s0 + c] = tile[pc][r];
  }
}

// ---------------- GEMM: C[M][N] = A[M][K] * Bt[N][K]^T ----------------

template<int OUTF32>
__global__ __launch_bounds__(256) void k_gemm_bt(
    const unsigned short* __restrict__ A, const unsigned short* __restrict__ Bt,
    void* __restrict__ Cp, int M, int N, int K) {
  __shared__ __attribute__((aligned(16))) unsigned short As[128 * 32];
  __shared__ __attribute__((aligned(16))) unsigned short Bs[128 * 32];
  const int t = threadIdx.x;
  const int wave = t >> 6, lane = t & 63;
  const int lr = lane & 15, lg = lane >> 4;
  const int bm = blockIdx.x * 128, bn = blockIdx.y * 128;
  const int wr = (wave >> 1) * 64, wc = (wave & 1) * 64;
  f32x4 acc[4][4];
#pragma unroll
  for (int i = 0; i < 4; ++i)
#pragma unroll
    for (int j = 0; j < 4; ++j) acc[i][j] = (f32x4){0.f, 0.f, 0.f, 0.f};

  for (int k0 = 0; k0 < K; k0 += 32) {
    __syncthreads();
#pragma unroll
    for (int i = 0; i < 2; ++i) {
      const int cb = (wave * 2 + i) * 64;
      const int c = cb + lane;
      const int row = c >> 2, kc = c & 3;
      const int ksw = (kc ^ (row & 3)) * 8;
      GLDS16(A + (size_t)(bm + row) * K + k0 + ksw, (char*)As + cb * 16);
      GLDS16(Bt + (size_t)(bn + row) * K + k0 + ksw, (char*)Bs + cb * 16);
    }
    asm volatile("s_waitcnt vmcnt(0)" ::: "memory");
    __syncthreads();
    bf16x8 af[4], bfr[4];
#pragma unroll
    for (int mi = 0; mi < 4; ++mi) {
      const int row = wr + mi * 16 + lr;
      af[mi] = *(const bf16x8*)(As + row * 32 + ((lg ^ (lr & 3)) * 8));
    }
#pragma unroll
    for (int ni = 0; ni < 4; ++ni) {
      const int row = wc + ni * 16 + lr;
      bfr[ni] = *(const bf16x8*)(Bs + row * 32 + ((lg ^ (lr & 3)) * 8));
    }
#pragma unroll
    for (int mi = 0; mi < 4; ++mi)
#pragma unroll
      for (int ni = 0; ni < 4; ++ni)
        acc[mi][ni] = __builtin_amdgcn_mfma_f32_16x16x32_bf16(af[mi], bfr[ni], acc[mi][ni], 0, 0, 0);
  }
#pragma unroll
  for (int mi = 0; mi < 4; ++mi)
#pragma unroll
    for (int ni = 0; ni < 4; ++ni)
#pragma unroll
      for (int r = 0; r < 4; ++r) {
        const int m = bm + wr + mi * 16 + lg * 4 + r;
        const int n = bn + wc + ni * 16 + lr;
        if (OUTF32) ((float*)Cp)[(size_t)m * N + n] = acc[mi][ni][r];
        else ((unsigned short*)Cp)[(size_t)m * N + n] = f2bf(acc[mi][ni][r]);
      }
}

// ---------------- fused causal gated attention (v3) ----------------

#define STAGE_KV(kt_, buf_) do { \
  const int kv0_ = (kt_) * 64; \
  _Pragma("unroll") \
  for (int i_ = 0; i_ < 4; ++i_) { \
    const int cb_ = (wave * 4 + i_) * 64; \
    const int c_ = cb_ + lane; \
    { const int row_ = c_ >> 4, kc_ = c_ & 15; \
      GLDS16(Kp + (size_t)(kv0_ + row_) * LDQKV + ((kc_ ^ (row_ & 7)) * 8), \
             (char*)Ks[buf_] + cb_ * 16); } \
    { const int d_ = c_ >> 3, kc_ = c_ & 7; \
      GLDS16(Vp + (size_t)d_ * S_LEN + kv0_ + ((kc_ ^ (d_ & 7)) * 8), \
             (char*)Vs[buf_] + cb_ * 16); } \
  } \
} while (0)

template<bool DIAG>
__device__ __forceinline__ void attn_tile(
    const unsigned short* Kb, const unsigned short* Vb,
    unsigned short (*PsW)[72], const float* __restrict__ gate,
    int kv0, int qbase, const bf16x8* qf,
    f32x4* acc, f32x4& acc_s, float* mrow, int lr, int lg,
    const bf16x8 vb_ones) {
  // gate values for this tile's kv columns (logical k = cf*16+lr)
  float g4[4];
#pragma unroll
  for (int cf = 0; cf < 4; ++cf) g4[cf] = gate[kv0 + cf * 16 + lr];

  // Q.K^T : 16x64 scores (exp2-domain; scale pre-folded into Q)
  f32x4 sc[4];
  __builtin_amdgcn_s_setprio(1);
#pragma unroll
  for (int cf = 0; cf < 4; ++cf) {
    sc[cf] = (f32x4){0.f, 0.f, 0.f, 0.f};
    const int row = cf * 16 + lr;
#pragma unroll
    for (int ks = 0; ks < 4; ++ks) {
      bf16x8 kb = *(const bf16x8*)(Kb + row * 128 + (((ks * 4 + lg) ^ (lr & 7)) * 8));
      sc[cf] = __builtin_amdgcn_mfma_f32_16x16x32_bf16(qf[ks], kb, sc[cf], 0, 0, 0);
    }
  }
  __builtin_amdgcn_s_setprio(0);

  if (DIAG) {
#pragma unroll
    for (int cf = 0; cf < 4; ++cf) {
      const int kpos = kv0 + cf * 16 + lr;
#pragma unroll
      for (int r = 0; r < 4; ++r)
        sc[cf][r] = (kpos <= qbase + r) ? sc[cf][r] : -3e38f;
    }
  }
  float lmax[4];
#pragma unroll
  for (int r = 0; r < 4; ++r)
    lmax[r] = fmaxf(fmaxf(sc[0][r], sc[1][r]), fmaxf(sc[2][r], sc[3][r]));

  // defer-max: rescale only when a row max grew past m + 8*log2e
  bool need = (lmax[0] > mrow[0] + 11.5416f) | (lmax[1] > mrow[1] + 11.5416f) |
              (lmax[2] > mrow[2] + 11.5416f) | (lmax[3] > mrow[3] + 11.5416f);
  if (__any(need)) {
    float tm[4] = {lmax[0], lmax[1], lmax[2], lmax[3]};
#pragma unroll
    for (int off = 8; off; off >>= 1)
#pragma unroll
      for (int r = 0; r < 4; ++r) tm[r] = fmaxf(tm[r], __shfl_xor(tm[r], off));
#pragma unroll
    for (int r = 0; r < 4; ++r) {
      const float mn = fmaxf(mrow[r], tm[r]);
      const float alpha = __builtin_amdgcn_exp2f(mrow[r] - mn);
      mrow[r] = mn;
#pragma unroll
      for (int j = 0; j < 8; ++j) acc[j][r] *= alpha;
      acc_s[r] *= alpha;
    }
  }
  // p = exp2(sc - m) * gate ; pack to bf16 pairs, write P^pi rows
#pragma unroll
  for (int r = 0; r < 4; ++r) {
    float p0 = __builtin_amdgcn_exp2f(sc[0][r] - mrow[r]) * g4[0];
    float p1 = __builtin_amdgcn_exp2f(sc[1][r] - mrow[r]) * g4[1];
    float p2 = __builtin_amdgcn_exp2f(sc[2][r] - mrow[r]) * g4[2];
    float p3 = __builtin_amdgcn_exp2f(sc[3][r] - mrow[r]) * g4[3];
    uint2 pk = { cvt_pk_bf16(p0, p1), cvt_pk_bf16(p2, p3) };
    *(uint2*)(&PsW[lg * 4 + r][lr * 4]) = pk;
  }
  asm volatile("s_waitcnt lgkmcnt(0)" ::: "memory");
  __builtin_amdgcn_sched_barrier(0);
  // P.V : accumulate 16x128 (+ ones-column MFMA accumulates the row sum)
  __builtin_amdgcn_s_setprio(1);
#pragma unroll
  for (int ks = 0; ks < 2; ++ks) {
    bf16x8 pa = *(const bf16x8*)(&PsW[lr][ks * 32 + lg * 8]);
#pragma unroll
    for (int j = 0; j < 8; ++j) {
      const int d = j * 16 + lr;
      bf16x8 vb = *(const bf16x8*)(Vb + d * 64 + (((ks * 4 + lg) ^ (lr & 7)) * 8));
      acc[j] = __builtin_amdgcn_mfma_f32_16x16x32_bf16(pa, vb, acc[j], 0, 0, 0);
    }
    acc_s = __builtin_amdgcn_mfma_f32_16x16x32_bf16(pa, vb_ones, acc_s, 0, 0, 0);
  }
  __builtin_amdgcn_s_setprio(0);
}

__global__ __launch_bounds__(256) void k_attn(
    const unsigned short* __restrict__ QKV, const unsigned short* __restrict__ Vt,
    const float* __restrict__ gate, unsigned short* __restrict__ Oattn) {
  __shared__ __attribute__((aligned(16))) unsigned short Ks[2][64 * 128];
  __shared__ __attribute__((aligned(16))) unsigned short Vs[2][128 * 64];
  __shared__ __attribute__((aligned(16))) unsigned short Ps[4][16][72];
  const int h = blockIdx.y, kvh = h >> 2;
  const int bx = blockIdx.x;           // 0..31
  const int t = threadIdx.x, wave = t >> 6, lane = t & 63;
  const int lr = lane & 15, lg = lane >> 4;
  const unsigned short* Qp = QKV + h * HD;
  const unsigned short* Kp = QKV + DMODEL + kvh * HD;
  const unsigned short* Vp = Vt + (size_t)kvh * HD * S_LEN;
  unsigned short (*PsW)[72] = Ps[wave];
  bf16x8 vb_ones;
  {
    const short one = (short)0x3F80, z = 0;
    const short e = (lr == 0) ? one : z;
    vb_ones = (bf16x8){e, e, e, e, e, e, e, e};
  }

  for (int half = 0; half < 2; ++half) {
    const int qt = half ? bx : (63 - bx);   // heavy tile first
    const int q0 = qt * 64;
    const int nt = qt + 1;
    const int qbase = q0 + wave * 16 + lg * 4;

    bf16x8 qf[4];
    {
      const size_t qoff = (size_t)(q0 + wave * 16 + lr) * LDQKV;
#pragma unroll
      for (int ks = 0; ks < 4; ++ks)
        qf[ks] = *(const bf16x8*)(Qp + qoff + ks * 32 + lg * 8);
    }
    f32x4 acc[8];
#pragma unroll
    for (int j = 0; j < 8; ++j) acc[j] = (f32x4){0.f, 0.f, 0.f, 0.f};
    f32x4 acc_s = (f32x4){0.f, 0.f, 0.f, 0.f};
    float mrow[4] = {-3e38f, -3e38f, -3e38f, -3e38f};

    __builtin_amdgcn_s_barrier();        // protect buf0 from previous half's reads
    STAGE_KV(0, 0);

    for (int kt = 0; kt < nt - 1; ++kt) {
      STAGE_KV(kt + 1, (kt + 1) & 1);
      asm volatile("s_waitcnt vmcnt(8)" ::: "memory");
      __builtin_amdgcn_s_barrier();
      attn_tile<false>(Ks[kt & 1], Vs[kt & 1], PsW, gate, kt * 64, qbase,
                       qf, acc, acc_s, mrow, lr, lg, vb_ones);
      __builtin_amdgcn_s_barrier();
    }
    // diagonal tile
    asm volatile("s_waitcnt vmcnt(0)" ::: "memory");
    __builtin_amdgcn_s_barrier();
    attn_tile<true>(Ks[(nt - 1) & 1], Vs[(nt - 1) & 1], PsW, gate, (nt - 1) * 64,
                    qbase, qf, acc, acc_s, mrow, lr, lg, vb_ones);
    __builtin_amdgcn_s_barrier();

    float inv[4];
#pragma unroll
    for (int r = 0; r < 4; ++r)
      inv[r] = 1.0f / __shfl(acc_s[r], lane & 48);
#pragma unroll
    for (int j = 0; j < 8; ++j)
#pragma unroll
      for (int r = 0; r < 4; ++r) {
        const int m = qbase + r;
        Oattn[(size_t)m * DMODEL + h * HD + j * 16 + lr] = f2bf(acc[j][r] * inv[r]);
      }
  }
}

// ---------------- launch ----------------

extern "C" void kernel_launch(void* const* d_in, const int* in_sizes, int n_in,
                              void* d_out, int out_size, void* d_ws, size_t ws_size,
                              hipStream_t stream) {
  (void)in_sizes; (void)n_in; (void)out_size; (void)ws_size;
  const float* hid  = (const float*)d_in[0];
  // d_in[1] = attention_mask (pure causal; recomputed inline, never read)
  const float* cosp = (const float*)d_in[2];
  const float* sinp = (const float*)d_in[3];
  const float* gate = (const float*)d_in[4];
  const float* Wq   = (const float*)d_in[5];
  const float* Wk   = (const float*)d_in[6];
  const float* Wv   = (const float*)d_in[7];
  const float* Wo   = (const float*)d_in[8];
  float* out = (float*)d_out;
  char* ws = (char*)d_ws;
  unsigned short* Xb   = (unsigned short*)(ws);                       // 16 MB  [4096][2048] bf16
  unsigned short* Wt   = (unsigned short*)(ws + (size_t)16777216);    // 12 MB  [3072][2048] bf16 (Wq|Wk|Wv)^T
  unsigned short* Wot  = (unsigned short*)(ws + (size_t)29360128);    //  8 MB  [2048][2048] bf16 Wo^T
  unsigned short* QKV  = (unsigned short*)(ws + (size_t)37748736);    // 24 MB  [4096][3072] bf16
  unsigned short* Oatt = (unsigned short*)(ws + (size_t)62914560);    // 16 MB  [4096][2048] bf16
  unsigned short* Vt   = (unsigned short*)(ws + (size_t)79691776);    //  4 MB  [4][128][4096] bf16

  k_cast_bf16<<<8192, 256, 0, stream>>>(hid, Xb, 2097152);
  k_transpose_bf16<<<dim3(32, 32), 256, 0, stream>>>(Wq, Wt, 2048, 2048);
  k_transpose_bf16<<<dim3(32, 8), 256, 0, stream>>>(Wk, Wt + (size_t)2048 * 2048, 2048, 512);
  k_transpose_bf16<<<dim3(32, 8), 256, 0, stream>>>(Wv, Wt + (size_t)2560 * 2048, 2048, 512);
  k_transpose_bf16<<<dim3(32, 32), 256, 0, stream>>>(Wo, Wot, 2048, 2048);
  k_gemm_bt<0><<<dim3(32, 24), 256, 0, stream>>>(Xb, Wt, QKV, 4096, 3072, 2048);
  k_rope<<<20480, 256, 0, stream>>>(QKV, cosp, sinp);
  k_transpose_v<<<dim3(64, 8), 256, 0, stream>>>(QKV, Vt);
  k_attn<<<dim3(32, 16), 256, 0, stream>>>(QKV, Vt, gate, Oatt);
  k_gemm_bt<1><<<dim3(32, 16), 256, 0, stream>>>(Oatt, Wot, out, 4096, 2048, 2048);
}